// Round 1
// baseline (1191.822 us; speedup 1.0000x reference)
//
#include <hip/hip_runtime.h>
#include <hip/hip_fp16.h>

typedef unsigned int u32;
typedef _Float16 h2f __attribute__((ext_vector_type(2)));

#define BB 128
#define TT 512
#define DD 64
#define NBL 32
#define GIN 2080

// sign of e_i * e_j in Cl(4,1): returns 1 if negative, 0 if positive
__device__ inline int gp_negbit(int i, int j) {
  int sw = 0;
#pragma unroll
  for (int b = 0; b < 5; ++b)
    if ((j >> b) & 1) sw += __popc(i >> (b + 1));
  return (sw ^ ((i & j) >> 4)) & 1;  // METRIC[4] = -1
}

__device__ inline float fdot2f(u32 a, u32 b, float acc) {
#if __has_builtin(__builtin_amdgcn_fdot2)
  return __builtin_amdgcn_fdot2(__builtin_bit_cast(h2f, a),
                                __builtin_bit_cast(h2f, b), acc, false);
#else
  h2f av = __builtin_bit_cast(h2f, a), bv = __builtin_bit_cast(h2f, b);
  return acc + (float)av.x * (float)bv.x + (float)av.y * (float)bv.y;
#endif
}

__device__ inline u32 pkf16(float a, float b) {
  return __builtin_bit_cast(u32, __builtin_amdgcn_cvt_pkrtz(a, b));
}

__global__ __launch_bounds__(512, 2) void versor_main(
    const int* __restrict__ x, const float* __restrict__ emb,
    const float* __restrict__ gate_w, const float* __restrict__ gate_b,
    float* __restrict__ ws_h) {
  __shared__ __align__(16) float rn[4][NBL];      // normalized emb rows
  __shared__ float rc[4][DD];                     // r-part of gate, pre-dotted
  __shared__ int x_lds[TT];
  __shared__ __align__(16) float h32[2][DD][36];  // fp32 h, padded rows
  __shared__ __align__(16) u32 h16t[2][16][68];   // f16x2 h, transposed [pair][d]

  const int b = blockIdx.x;
  const int tid = threadIdx.x;
  const int w = tid >> 6;        // wave 0..7
  const int l = tid & 63;        // lane
  const int c16 = l & 15;        // gate column slice
  const int p4 = l >> 4;         // gate row-pair within wave (0..3)
  const int rloc = l >> 3;       // 0..7
  const int d = (w << 3) + rloc; // this lane's GP row
  const int c = l & 7;           // GP base blade
  const int b3 = rloc & 1;

  // ---- init: normalized embeddings (only 4 distinct r vectors) ----
  if (tid < 4) {
    float v[NBL];
    float s = 0.f;
    for (int i = 0; i < NBL; ++i) { v[i] = emb[tid * NBL + i]; s += v[i] * v[i]; }
    float sc = 1.f / (sqrtf(s) + 1e-8f);
    for (int i = 0; i < NBL; ++i) rn[tid][i] = v[i] * sc;
  }
  if (tid < TT) x_lds[tid] = x[b * TT + tid];
  for (int idx = tid; idx < DD * 36; idx += 512) {
    int dd = idx / 36, jj = idx - dd * 36;
    h32[0][dd][jj] = (jj == 0) ? 1.f : 0.f;
  }
  for (int idx = tid; idx < 16 * 68; idx += 512) {
    int m = idx / 68, dd = idx - m * 68;
    h16t[0][m][dd] = (m == 0 && dd < 64) ? 0x00003C00u : 0u; // pack(1.0h, 0)
  }
  __syncthreads();

  // ---- rc[e][row] = sum_i gate_w[row][2048+i] * rn[e][i] ----
  if (tid < 256) {
    int e = tid >> 6, row = tid & 63;
    float s = 0.f;
    for (int i = 0; i < NBL; ++i) s += gate_w[row * GIN + 2048 + i] * rn[e][i];
    rc[e][row] = s;
  }

  // ---- gate weights -> registers (f16x2). lane covers dwords {16j + c16} ----
  u32 gw[2][64];
#pragma unroll
  for (int rr = 0; rr < 2; ++rr) {
    const int row = (w << 3) + (p4 << 1) + rr;
    const float* wp = gate_w + row * GIN + 2 * c16;
#pragma unroll
    for (int j = 0; j < 64; ++j) {
      gw[rr][j] = pkf16(wp[32 * j], wp[32 * j + 1]);
    }
  }
  const float gb = gate_b[d];

  // ---- per-lane sign masks for k=c; k+8/+16 flip for i>=16, k+24 never ----
  u32 sb[NBL];
#pragma unroll
  for (int i = 0; i < NBL; ++i) sb[i] = gp_negbit(i, i ^ c) ? 0x80000000u : 0u;
  __syncthreads();

  // ================= recurrence =================
  for (int t = 0; t < TT; ++t) {
    const int p = t & 1;
    const int pn = p ^ 1;
    const int xi = x_lds[t];

    // ---- gate: 2 rows x 64 dwords of f16 dot2 ----
    float ac0 = 0.f, ac1 = 0.f;
#pragma unroll
    for (int jq = 0; jq < 16; ++jq) {
      uint4 hv = *(const uint4*)&h16t[p][c16][4 * jq];
      ac0 = fdot2f(gw[0][4 * jq + 0], hv.x, ac0);
      ac0 = fdot2f(gw[0][4 * jq + 1], hv.y, ac0);
      ac0 = fdot2f(gw[0][4 * jq + 2], hv.z, ac0);
      ac0 = fdot2f(gw[0][4 * jq + 3], hv.w, ac0);
      ac1 = fdot2f(gw[1][4 * jq + 0], hv.x, ac1);
      ac1 = fdot2f(gw[1][4 * jq + 1], hv.y, ac1);
      ac1 = fdot2f(gw[1][4 * jq + 2], hv.z, ac1);
      ac1 = fdot2f(gw[1][4 * jq + 3], hv.w, ac1);
    }
#pragma unroll
    for (int off = 1; off <= 8; off <<= 1) {
      ac0 += __shfl_xor(ac0, off, 64);
      ac1 += __shfl_xor(ac1, off, 64);
    }
    float zg = (b3 ? ac1 : ac0) + rc[xi][d] + gb;
    float g = 1.f / (1.f + exp2f(-1.44269504f * zg));

    // ---- geometric product: hp[m] = h[d][m^c] (static reg indices) ----
    float hp[NBL];
#pragma unroll
    for (int m = 0; m < NBL; ++m) hp[m] = h32[p][d][m ^ c];

    const float4* rp = (const float4*)&rn[xi][0];
    float a0 = 0.f, a1 = 0.f, a2 = 0.f, a3 = 0.f;
#pragma unroll
    for (int q = 0; q < 8; ++q) {
      float4 rv = rp[q];
      float r4[4] = {rv.x, rv.y, rv.z, rv.w};
#pragma unroll
      for (int u = 0; u < 4; ++u) {
        const int i = q * 4 + u;
        float tmp = __builtin_bit_cast(
            float, __builtin_bit_cast(u32, r4[u]) ^ sb[i]);
        a0 = fmaf(tmp, hp[i], a0);            // k = c
        if (i < 16) {
          a1 = fmaf(tmp, hp[i ^ 8], a1);      // k = c+8
          a2 = fmaf(tmp, hp[i ^ 16], a2);     // k = c+16
        } else {
          a1 = fmaf(-tmp, hp[i ^ 8], a1);
          a2 = fmaf(-tmp, hp[i ^ 16], a2);
        }
        a3 = fmaf(tmp, hp[i ^ 24], a3);       // k = c+24
      }
    }

    // ---- gated update + mnorm over the 8-lane d-group ----
    float u0 = fmaf(g, a0 - hp[0], hp[0]);
    float u1 = fmaf(g, a1 - hp[8], hp[8]);
    float u2 = fmaf(g, a2 - hp[16], hp[16]);
    float u3 = fmaf(g, a3 - hp[24], hp[24]);
    float sq = u0 * u0 + u1 * u1 + u2 * u2 + u3 * u3;
    sq += __shfl_xor(sq, 1, 64);
    sq += __shfl_xor(sq, 2, 64);
    sq += __shfl_xor(sq, 4, 64);
    float sc = 1.f / (sqrtf(sq) + 1e-8f);
    u0 *= sc; u1 *= sc; u2 *= sc; u3 *= sc;

    h32[pn][d][c] = u0;
    h32[pn][d][c + 8] = u1;
    h32[pn][d][c + 16] = u2;
    h32[pn][d][c + 24] = u3;

    float v0 = __shfl_xor(u0, 1, 64);
    float v1 = __shfl_xor(u1, 1, 64);
    float v2 = __shfl_xor(u2, 1, 64);
    float v3 = __shfl_xor(u3, 1, 64);
    if (!(l & 1)) {  // even c packs (c, c+1)
      h16t[pn][(c) >> 1][d] = pkf16(u0, v0);
      h16t[pn][(c + 8) >> 1][d] = pkf16(u1, v1);
      h16t[pn][(c + 16) >> 1][d] = pkf16(u2, v2);
      h16t[pn][(c + 24) >> 1][d] = pkf16(u3, v3);
    }
    __syncthreads();
  }

  // final h is in buffer 0 (t=511: p=1, wrote pn=0)
  for (int idx = tid; idx < DD * NBL; idx += 512) {
    int dd = idx >> 5, jj = idx & 31;
    ws_h[b * 2048 + idx] = h32[0][dd][jj];
  }
}

__global__ __launch_bounds__(128) void versor_head(
    const float* __restrict__ ws_h, const float* __restrict__ w1,
    const float* __restrict__ b1, const float* __restrict__ ln_g,
    const float* __restrict__ ln_b, const float* __restrict__ w2,
    const float* __restrict__ b2, float* __restrict__ out) {
  __shared__ __align__(16) float hs[2048];
  __shared__ float red[8];
  const int b = blockIdx.x;
  const int j = threadIdx.x;
  for (int idx = j; idx < 2048; idx += 128) hs[idx] = ws_h[b * 2048 + idx];
  __syncthreads();

  float acc = b1[j];
  const float4* w4 = (const float4*)(w1 + j * 2048);
  const float4* h4 = (const float4*)hs;
#pragma unroll 4
  for (int k = 0; k < 512; ++k) {
    float4 wv = w4[k];
    float4 hv = h4[k];
    acc = fmaf(hv.x, wv.x, acc);
    acc = fmaf(hv.y, wv.y, acc);
    acc = fmaf(hv.z, wv.z, acc);
    acc = fmaf(hv.w, wv.w, acc);
  }

  float s1 = acc, s2 = acc * acc;
#pragma unroll
  for (int off = 1; off <= 32; off <<= 1) {
    s1 += __shfl_xor(s1, off, 64);
    s2 += __shfl_xor(s2, off, 64);
  }
  const int wid = j >> 6;
  if ((j & 63) == 0) { red[wid] = s1; red[4 + wid] = s2; }
  __syncthreads();
  float tot1 = red[0] + red[1], tot2 = red[4] + red[5];
  float mu = tot1 * (1.f / 128.f);
  float var = tot2 * (1.f / 128.f) - mu * mu;
  float z = (acc - mu) * rsqrtf(var + 1e-5f) * ln_g[j] + ln_b[j];
  z = fmaxf(z, 0.f);
  __syncthreads();

  float p0 = z * w2[j], p1 = z * w2[128 + j];
#pragma unroll
  for (int off = 1; off <= 32; off <<= 1) {
    p0 += __shfl_xor(p0, off, 64);
    p1 += __shfl_xor(p1, off, 64);
  }
  if ((j & 63) == 0) { red[wid] = p0; red[4 + wid] = p1; }
  __syncthreads();
  if (j == 0) {
    out[b * 2 + 0] = red[0] + red[1] + b2[0];
    out[b * 2 + 1] = red[4] + red[5] + b2[1];
  }
}

extern "C" void kernel_launch(void* const* d_in, const int* in_sizes, int n_in,
                              void* d_out, int out_size, void* d_ws,
                              size_t ws_size, hipStream_t stream) {
  (void)in_sizes; (void)n_in; (void)out_size; (void)ws_size;
  const int* x = (const int*)d_in[0];
  const float* emb = (const float*)d_in[1];
  const float* gate_w = (const float*)d_in[2];
  const float* gate_b = (const float*)d_in[3];
  const float* w1 = (const float*)d_in[4];
  const float* b1 = (const float*)d_in[5];
  const float* ln_g = (const float*)d_in[6];
  const float* ln_b = (const float*)d_in[7];
  const float* w2 = (const float*)d_in[8];
  const float* b2 = (const float*)d_in[9];
  // d_in[10] = gp_table (signs recomputed on device)
  float* out = (float*)d_out;
  float* ws_h = (float*)d_ws;  // 128*2048 floats = 1 MB

  versor_main<<<dim3(BB), dim3(512), 0, stream>>>(x, emb, gate_w, gate_b, ws_h);
  versor_head<<<dim3(BB), dim3(128), 0, stream>>>(ws_h, w1, b1, ln_g, ln_b, w2,
                                                  b2, out);
}

// Round 2
// 992.232 us; speedup vs baseline: 1.2012x; 1.2012x over previous
//
#include <hip/hip_runtime.h>
#include <hip/hip_fp16.h>

typedef unsigned int u32;
typedef _Float16 h2f __attribute__((ext_vector_type(2)));

#define BB 128
#define TT 512
#define DD 64
#define NBL 32
#define GIN 2080

// DPP controls: quad_perm xor1 = 0xB1, xor2 = 0x4E, half_mirror(xor7 in 8) =
// 0x141, row_mirror(xor15 in 16) = 0x140. All VALU-pipe (frees DS pipe).
template <int CTRL>
__device__ __forceinline__ float dpp_mov_f(float x) {
  return __builtin_bit_cast(
      float, __builtin_amdgcn_update_dpp(0, __builtin_bit_cast(int, x), CTRL,
                                         0xF, 0xF, true));
}
template <int CTRL>
__device__ __forceinline__ float dpp_add_f(float x) {
  return x + dpp_mov_f<CTRL>(x);
}
// xor16 within 32-lane group (DS pipe, 1 op)
__device__ __forceinline__ float swz_add16(float x) {
  return x + __builtin_bit_cast(float, __builtin_amdgcn_ds_swizzle(
                                           __builtin_bit_cast(int, x), 0x401F));
}

// sign of e_i * e_j in Cl(4,1): 1 if negative
__device__ inline int gp_negbit(int i, int j) {
  int sw = 0;
#pragma unroll
  for (int b = 0; b < 5; ++b)
    if ((j >> b) & 1) sw += __popc(i >> (b + 1));
  return (sw ^ ((i & j) >> 4)) & 1;  // METRIC[4] = -1
}

__device__ inline float fdot2f(u32 a, u32 b, float acc) {
#if __has_builtin(__builtin_amdgcn_fdot2)
  return __builtin_amdgcn_fdot2(__builtin_bit_cast(h2f, a),
                                __builtin_bit_cast(h2f, b), acc, false);
#else
  h2f av = __builtin_bit_cast(h2f, a), bv = __builtin_bit_cast(h2f, b);
  return acc + (float)av.x * (float)bv.x + (float)av.y * (float)bv.y;
#endif
}

__device__ inline u32 pkf16(float a, float b) {
  return __builtin_bit_cast(u32, __builtin_amdgcn_cvt_pkrtz(a, b));
}

__global__ __launch_bounds__(512, 2) void versor_main(
    const int* __restrict__ x, const float* __restrict__ emb,
    const float* __restrict__ gate_w, const float* __restrict__ gate_b,
    float* __restrict__ ws_h) {
  __shared__ float rn[4][NBL];                    // normalized emb rows
  __shared__ __align__(16) float rnq[4][8][4];    // rnq[e][q][j] = rn[e][q+8j]
  __shared__ float rc[4][DD];                     // r-part of gate, pre-dotted
  __shared__ int x_lds[TT];
  // h32 owner-quad-major: [d][o][j] = h[d][o + 8j], row stride 36 (b128-safe)
  __shared__ __align__(16) float h32[2][DD][36];
  __shared__ __align__(16) u32 h16t[2][16][68];   // f16x2 h transposed [pair][d]

  const int b = blockIdx.x;
  const int tid = threadIdx.x;
  const int w = tid >> 6;         // wave 0..7
  const int l = tid & 63;         // lane
  const int rl = l >> 3;          // 0..7
  const int d = (w << 3) + rl;    // this lane's row
  const int c = l & 7;            // GP owner quad / base blade
  const int r2g = l >> 5;         // gate row-quad group within wave (0..1)
  const int s = l & 31;           // gate 32-dword column slice

  // ---- init: normalized embeddings (only 4 distinct r vectors) ----
  if (tid < 4) {
    float v[NBL];
    float sum = 0.f;
    for (int i = 0; i < NBL; ++i) { v[i] = emb[tid * NBL + i]; sum += v[i] * v[i]; }
    float sc = 1.f / (sqrtf(sum) + 1e-8f);
    for (int i = 0; i < NBL; ++i) rn[tid][i] = v[i] * sc;
    for (int q = 0; q < 8; ++q)
      for (int j = 0; j < 4; ++j) rnq[tid][q][j] = v[q + 8 * j] * sc;
  }
  if (tid < TT) x_lds[tid] = x[b * TT + tid];
  for (int idx = tid; idx < DD * 36; idx += 512) {
    int dd = idx / 36, jj = idx - dd * 36;
    h32[0][dd][jj] = (jj == 0) ? 1.f : 0.f;   // e0: owner 0, slot 0
  }
  for (int idx = tid; idx < 16 * 68; idx += 512) {
    int m = idx / 68, dd = idx - m * 68;
    h16t[0][m][dd] = (m == 0 && dd < 64) ? 0x00003C00u : 0u;  // pack(1.0h, 0)
  }
  __syncthreads();

  // ---- rc[e][row] = sum_i gate_w[row][2048+i] * rn[e][i] ----
  if (tid < 256) {
    int e = tid >> 6, row = tid & 63;
    float sum = 0.f;
    for (int i = 0; i < NBL; ++i) sum += gate_w[row * GIN + 2048 + i] * rn[e][i];
    rc[e][row] = sum;
  }

  // ---- gate weights -> registers (f16x2), 4 rows x 32 dwords per lane ----
  // lane covers rows 8w + 4*r2g + rr, h16-dwords [32s, 32s+32)
  u32 gw[4][32];
#pragma unroll
  for (int rr = 0; rr < 4; ++rr) {
    const int row = (w << 3) + (r2g << 2) + rr;
    const float* wp = gate_w + row * GIN;
#pragma unroll
    for (int m = 0; m < 32; ++m) {
      int Dd = 32 * s + m;            // h16 dword index = pair*64 + d
      int pair = Dd >> 6, dd = Dd & 63;
      int col = dd * 32 + 2 * pair;
      gw[rr][m] = pkf16(wp[col], wp[col + 1]);
    }
  }
  const float gb = gate_b[d];

  // ---- per-lane sign masks for k=c (i-indexed) ----
  u32 sb[NBL];
#pragma unroll
  for (int i = 0; i < NBL; ++i) sb[i] = gp_negbit(i, i ^ c) ? 0x80000000u : 0u;
  __syncthreads();

  // ================= recurrence =================
  for (int t = 0; t < TT; ++t) {
    const int p = t & 1;
    const int pn = p ^ 1;
    const int xi = x_lds[t];

    // ---- gate: 4 rows x 32 dwords of f16 dot2 ----
    const u32* Hb = &h16t[p][s >> 1][(s & 1) << 5];
    float a0 = 0.f, a1 = 0.f, a2 = 0.f, a3 = 0.f;
#pragma unroll
    for (int jq = 0; jq < 8; ++jq) {
      uint4 hv = *(const uint4*)(Hb + (jq << 2));
      a0 = fdot2f(gw[0][4 * jq + 0], hv.x, a0);
      a0 = fdot2f(gw[0][4 * jq + 1], hv.y, a0);
      a0 = fdot2f(gw[0][4 * jq + 2], hv.z, a0);
      a0 = fdot2f(gw[0][4 * jq + 3], hv.w, a0);
      a1 = fdot2f(gw[1][4 * jq + 0], hv.x, a1);
      a1 = fdot2f(gw[1][4 * jq + 1], hv.y, a1);
      a1 = fdot2f(gw[1][4 * jq + 2], hv.z, a1);
      a1 = fdot2f(gw[1][4 * jq + 3], hv.w, a1);
      a2 = fdot2f(gw[2][4 * jq + 0], hv.x, a2);
      a2 = fdot2f(gw[2][4 * jq + 1], hv.y, a2);
      a2 = fdot2f(gw[2][4 * jq + 2], hv.z, a2);
      a2 = fdot2f(gw[2][4 * jq + 3], hv.w, a2);
      a3 = fdot2f(gw[3][4 * jq + 0], hv.x, a3);
      a3 = fdot2f(gw[3][4 * jq + 1], hv.y, a3);
      a3 = fdot2f(gw[3][4 * jq + 2], hv.z, a3);
      a3 = fdot2f(gw[3][4 * jq + 3], hv.w, a3);
    }
    // reduce over the 32 lanes of this r2g group (DPP for <=16, swizzle x16)
    a0 = dpp_add_f<0xB1>(a0); a0 = dpp_add_f<0x4E>(a0);
    a0 = dpp_add_f<0x141>(a0); a0 = dpp_add_f<0x140>(a0); a0 = swz_add16(a0);
    a1 = dpp_add_f<0xB1>(a1); a1 = dpp_add_f<0x4E>(a1);
    a1 = dpp_add_f<0x141>(a1); a1 = dpp_add_f<0x140>(a1); a1 = swz_add16(a1);
    a2 = dpp_add_f<0xB1>(a2); a2 = dpp_add_f<0x4E>(a2);
    a2 = dpp_add_f<0x141>(a2); a2 = dpp_add_f<0x140>(a2); a2 = swz_add16(a2);
    a3 = dpp_add_f<0xB1>(a3); a3 = dpp_add_f<0x4E>(a3);
    a3 = dpp_add_f<0x141>(a3); a3 = dpp_add_f<0x140>(a3); a3 = swz_add16(a3);
    const int jsel = rl & 3;
    float zv = (jsel == 0) ? a0 : (jsel == 1) ? a1 : (jsel == 2) ? a2 : a3;
    float zg = zv + rc[xi][d] + gb;
    float g = 1.f / (1.f + exp2f(-1.44269504f * zg));

    // ---- geometric product: hq[q] = (h[(q^c)+8j])_j = (hp[q+8j])_j ----
    float4 hq[8];
#pragma unroll
    for (int q = 0; q < 8; ++q)
      hq[q] = *(const float4*)&h32[p][d][(q ^ c) << 2];

    float b0 = 0.f, b1_ = 0.f, b2_ = 0.f, b3_ = 0.f;
#pragma unroll
    for (int q = 0; q < 8; ++q) {
      float4 rv = *(const float4*)&rnq[xi][q][0];
      float t0 = __builtin_bit_cast(float, __builtin_bit_cast(u32, rv.x) ^ sb[q]);
      float t1 = __builtin_bit_cast(float, __builtin_bit_cast(u32, rv.y) ^ sb[q + 8]);
      float t2 = __builtin_bit_cast(float, __builtin_bit_cast(u32, rv.z) ^ sb[q + 16]);
      float t3 = __builtin_bit_cast(float, __builtin_bit_cast(u32, rv.w) ^ sb[q + 24]);
      // j=0 (i=q): + + + +
      b0 = fmaf(t0, hq[q].x, b0);
      b1_ = fmaf(t0, hq[q].y, b1_);
      b2_ = fmaf(t0, hq[q].z, b2_);
      b3_ = fmaf(t0, hq[q].w, b3_);
      // j=1 (i=q+8): + + + +
      b0 = fmaf(t1, hq[q].y, b0);
      b1_ = fmaf(t1, hq[q].x, b1_);
      b2_ = fmaf(t1, hq[q].w, b2_);
      b3_ = fmaf(t1, hq[q].z, b3_);
      // j=2 (i=q+16): + - - +
      b0 = fmaf(t2, hq[q].z, b0);
      b1_ = fmaf(-t2, hq[q].w, b1_);
      b2_ = fmaf(-t2, hq[q].x, b2_);
      b3_ = fmaf(t2, hq[q].y, b3_);
      // j=3 (i=q+24): + - - +
      b0 = fmaf(t3, hq[q].w, b0);
      b1_ = fmaf(-t3, hq[q].z, b1_);
      b2_ = fmaf(-t3, hq[q].y, b2_);
      b3_ = fmaf(t3, hq[q].x, b3_);
    }

    // ---- gated update + mnorm over the 8-lane d-group (DPP) ----
    float u0 = fmaf(g, b0 - hq[0].x, hq[0].x);
    float u1 = fmaf(g, b1_ - hq[0].y, hq[0].y);
    float u2 = fmaf(g, b2_ - hq[0].z, hq[0].z);
    float u3 = fmaf(g, b3_ - hq[0].w, hq[0].w);
    float sq = u0 * u0 + u1 * u1 + u2 * u2 + u3 * u3;
    sq = dpp_add_f<0xB1>(sq);
    sq = dpp_add_f<0x4E>(sq);
    sq = dpp_add_f<0x141>(sq);
    float sc = 1.f / (sqrtf(sq) + 1e-8f);
    u0 *= sc; u1 *= sc; u2 *= sc; u3 *= sc;

    // owner-quad-major b128 store (was 4x b32)
    *(float4*)&h32[pn][d][c << 2] = make_float4(u0, u1, u2, u3);

    // f16x2 transposed copy for the gate (partner via DPP xor1)
    float v0 = dpp_mov_f<0xB1>(u0);
    float v1 = dpp_mov_f<0xB1>(u1);
    float v2 = dpp_mov_f<0xB1>(u2);
    float v3 = dpp_mov_f<0xB1>(u3);
    if (!(l & 1)) {  // even c packs (c, c+1)
      h16t[pn][(c) >> 1][d] = pkf16(u0, v0);
      h16t[pn][(c + 8) >> 1][d] = pkf16(u1, v1);
      h16t[pn][(c + 16) >> 1][d] = pkf16(u2, v2);
      h16t[pn][(c + 24) >> 1][d] = pkf16(u3, v3);
    }
    __syncthreads();
  }

  // final h is in buffer 0; convert owner-major -> blade order
  for (int idx = tid; idx < DD * NBL; idx += 512) {
    int dd = idx >> 5, blade = idx & 31;
    int o = blade & 7, j = blade >> 3;
    ws_h[b * 2048 + idx] = h32[0][dd][4 * o + j];
  }
}

// 32 blocks x 4 batches: w1 read 32x (32 MB through L3) instead of 128x
__global__ __launch_bounds__(512) void versor_head(
    const float* __restrict__ ws_h, const float* __restrict__ w1,
    const float* __restrict__ b1, const float* __restrict__ ln_g,
    const float* __restrict__ ln_b, const float* __restrict__ w2,
    const float* __restrict__ b2, float* __restrict__ out) {
  __shared__ __align__(16) float hs[4][2048];
  __shared__ float red[8][2];
  const int bb = blockIdx.x;
  const int tid = threadIdx.x;
  for (int idx = tid; idx < 8192; idx += 512)
    ((float*)hs)[idx] = ws_h[bb * 8192 + idx];
  __syncthreads();

  const int r = tid & 127;   // output row
  const int bs = tid >> 7;   // batch slot 0..3 (waves 2bs, 2bs+1)
  float acc = b1[r];
  const float4* w4 = (const float4*)(w1 + r * 2048);
  const float4* h4 = (const float4*)&hs[bs][0];
#pragma unroll 4
  for (int k = 0; k < 512; ++k) {
    float4 wv = w4[k];
    float4 hv = h4[k];
    acc = fmaf(hv.x, wv.x, acc);
    acc = fmaf(hv.y, wv.y, acc);
    acc = fmaf(hv.z, wv.z, acc);
    acc = fmaf(hv.w, wv.w, acc);
  }

  // LayerNorm stats per batch slot (2 waves each)
  float s1 = acc, s2 = acc * acc;
#pragma unroll
  for (int off = 1; off <= 32; off <<= 1) {
    s1 += __shfl_xor(s1, off, 64);
    s2 += __shfl_xor(s2, off, 64);
  }
  const int wv = tid >> 6;
  if ((tid & 63) == 0) { red[wv][0] = s1; red[wv][1] = s2; }
  __syncthreads();
  float t1 = red[2 * bs][0] + red[2 * bs + 1][0];
  float t2 = red[2 * bs][1] + red[2 * bs + 1][1];
  float mu = t1 * (1.f / 128.f);
  float var = t2 * (1.f / 128.f) - mu * mu;
  float z = (acc - mu) * rsqrtf(var + 1e-5f) * ln_g[r] + ln_b[r];
  z = fmaxf(z, 0.f);
  __syncthreads();

  float p0 = z * w2[r], p1 = z * w2[128 + r];
#pragma unroll
  for (int off = 1; off <= 32; off <<= 1) {
    p0 += __shfl_xor(p0, off, 64);
    p1 += __shfl_xor(p1, off, 64);
  }
  if ((tid & 63) == 0) { red[wv][0] = p0; red[wv][1] = p1; }
  __syncthreads();
  if ((tid & 127) == 0) {
    int bo = (bb * 4 + bs) * 2;
    out[bo + 0] = red[2 * bs][0] + red[2 * bs + 1][0] + b2[0];
    out[bo + 1] = red[2 * bs][1] + red[2 * bs + 1][1] + b2[1];
  }
}

extern "C" void kernel_launch(void* const* d_in, const int* in_sizes, int n_in,
                              void* d_out, int out_size, void* d_ws,
                              size_t ws_size, hipStream_t stream) {
  (void)in_sizes; (void)n_in; (void)out_size; (void)ws_size;
  const int* x = (const int*)d_in[0];
  const float* emb = (const float*)d_in[1];
  const float* gate_w = (const float*)d_in[2];
  const float* gate_b = (const float*)d_in[3];
  const float* w1 = (const float*)d_in[4];
  const float* b1 = (const float*)d_in[5];
  const float* ln_g = (const float*)d_in[6];
  const float* ln_b = (const float*)d_in[7];
  const float* w2 = (const float*)d_in[8];
  const float* b2 = (const float*)d_in[9];
  float* out = (float*)d_out;
  float* ws_h = (float*)d_ws;  // 128*2048 floats = 1 MB

  versor_main<<<dim3(BB), dim3(512), 0, stream>>>(x, emb, gate_w, gate_b, ws_h);
  versor_head<<<dim3(32), dim3(512), 0, stream>>>(ws_h, w1, b1, ln_g, ln_b, w2,
                                                  b2, out);
}